// Round 4
// baseline (90.800 us; speedup 1.0000x reference)
//
#include <hip/hip_runtime.h>

// LengthRegulator fused single-kernel:
//   out[b,p,:] = x[b, searchsorted_right(cumsum(dur[b]), p), :]  (0 when p >= mel_len[b])
//   mel_len written as float at d_out + B*MAXLEN*C.
// B=32, T=1024, C=384, MAX_LEN=8192. Durations arrive as int32.
// Each block: (batch b, chunk of 256 rows). Redundant 4KB duration load + LDS scan
// per block (~1us, overlapped) buys zero inter-kernel dependency + no global idx.

#define BB 32
#define TT 1024
#define CC 384
#define MAXLEN 8192
#define OUT0 (BB * MAXLEN * CC)          // 100663296 floats
#define NT 512                           // threads per block (8 waves)
#define ROWS_PER_BLK 256
#define NCHUNK (MAXLEN / ROWS_PER_BLK)   // 32
#define QPR (CC / 4)                     // 96 float4 per row
#define QPB (ROWS_PER_BLK * QPR)         // 24576 quads per block
#define ITERS (QPB / NT)                 // 48

typedef float f32x4 __attribute__((ext_vector_type(4)));

__global__ __launch_bounds__(NT) void lr_fused(const int* __restrict__ dur,
                                               const f32x4* __restrict__ x4,
                                               f32x4* __restrict__ out4,
                                               float* __restrict__ mel_out) {
    __shared__ int sd[TT];              // durations -> inclusive cumsum
    __shared__ int ss[NT];              // pair sums for scan
    __shared__ int sidx[ROWS_PER_BLK];  // gather index per row of this chunk
    const int b     = blockIdx.y;
    const int chunk = blockIdx.x;
    const int t     = threadIdx.x;

    // ---- load 1024 durations, scan (pair-sum + 512-wide Hillis-Steele) ----
    sd[t]      = dur[b * TT + t];
    sd[t + NT] = dur[b * TT + t + NT];
    __syncthreads();
    ss[t] = sd[2 * t] + sd[2 * t + 1];
    __syncthreads();
    #pragma unroll
    for (int off = 1; off < NT; off <<= 1) {
        int v = (t >= off) ? ss[t - off] : 0;
        __syncthreads();
        ss[t] += v;
        __syncthreads();
    }
    int inc = ss[t];            // inclusive scan of pair sums
    int d1  = sd[2 * t + 1];
    __syncthreads();
    sd[2 * t + 1] = inc;        // cum[2t+1]
    sd[2 * t]     = inc - d1;   // cum[2t]
    __syncthreads();
    const int ml = sd[TT - 1];
    if (chunk == 0 && t == 0) mel_out[b] = (float)ml;

    // ---- searchsorted_right for this chunk's 256 rows (into LDS) ----
    if (t < ROWS_PER_BLK) {
        int p = chunk * ROWS_PER_BLK + t;
        int r = -1;
        if (p < ml) {
            int lo = 0, hi = TT;
            while (lo < hi) {            // lo = count(cum <= p)
                int mid = (lo + hi) >> 1;
                if (sd[mid] <= p) lo = mid + 1; else hi = mid;
            }
            r = (lo < TT - 1) ? lo : (TT - 1);
        }
        sidx[t] = r;
    }
    __syncthreads();

    // ---- stream 256 rows x 96 quads; coalesced; nontemporal stores ----
    const f32x4* __restrict__ xb = x4 + (size_t)b * TT * QPR;
    f32x4* __restrict__ ob = out4 + (size_t)(b * MAXLEN + chunk * ROWS_PER_BLK) * QPR;
    #pragma unroll 4
    for (int k = 0; k < ITERS; ++k) {
        unsigned q    = (unsigned)t + (unsigned)k * NT;
        unsigned row  = q / QPR;         // compiler magic-mul, exact
        unsigned lane = q - row * QPR;
        int i = sidx[row];
        f32x4 v = (f32x4)0.f;
        if (i >= 0) v = xb[(unsigned)i * QPR + lane];
        __builtin_nontemporal_store(v, &ob[q]);
    }
}

extern "C" void kernel_launch(void* const* d_in, const int* in_sizes, int n_in,
                              void* d_out, int out_size, void* d_ws, size_t ws_size,
                              hipStream_t stream) {
    const float* x   = (const float*)d_in[0];
    const int*   dur = (const int*)d_in[1];   // int64 in reference -> int32 on device
    float* out = (float*)d_out;

    dim3 grid(NCHUNK, BB);   // (32, 32) = 1024 blocks
    lr_fused<<<grid, NT, 0, stream>>>(dur, (const f32x4*)x, (f32x4*)out, out + OUT0);
}

// Round 5
// 90.338 us; speedup vs baseline: 1.0051x; 1.0051x over previous
//
#include <hip/hip_runtime.h>

// LengthRegulator fused single-kernel, round 5:
//   out[b,p,:] = x[b, searchsorted_right(cumsum(dur[b]), p), :]  (0 when p >= mel_len[b])
//   mel_len written as float at d_out + B*MAXLEN*C.
// B=32, T=1024, C=384, MAX_LEN=8192. Durations arrive as int32.
// 2048 blocks x 256 threads; block -> (batch = bid>>6, chunk = bid&63, 128 rows).
// Scan prelude is wave-shuffle based (2 barriers, <1us) instead of Hillis-Steele
// over LDS (~20 barriers) -- that prelude was the R4 regression.

#define BB 32
#define TT 1024
#define CC 384
#define MAXLEN 8192
#define OUT0 (BB * MAXLEN * CC)   // 100663296 floats
#define NT 256                    // threads per block (4 waves)
#define ROWS 128                  // output rows per block
#define QPR (CC / 4)              // 96 float4 per row
#define ITERS (ROWS * QPR / NT)   // 48

typedef float f32x4 __attribute__((ext_vector_type(4)));

__global__ __launch_bounds__(NT) void lr_fused(const int4* __restrict__ dur4,
                                               const f32x4* __restrict__ x4,
                                               f32x4* __restrict__ out4,
                                               float* __restrict__ mel_out) {
    __shared__ int cum[TT];       // inclusive cumsum of durations
    __shared__ int sidx[ROWS];    // gather index per row of this chunk (-1 = masked)
    __shared__ int wsum[NT / 64]; // per-wave scan totals
    const int bid   = blockIdx.x;
    const int b     = bid >> 6;   // batch
    const int chunk = bid & 63;   // 64 chunks of 128 rows
    const int t     = threadIdx.x;
    const int lane  = t & 63;
    const int w     = t >> 6;

    // ---- fast scan: int4 load + serial 4-sum + wave shfl-scan + cross-wave fixup ----
    int4 d = dur4[b * (TT / 4) + t];
    int s0 = d.x;
    int s1 = s0 + d.y;
    int s2 = s1 + d.z;
    int s3 = s2 + d.w;
    int v = s3;
    #pragma unroll
    for (int dd = 1; dd < 64; dd <<= 1) {
        int u = __shfl_up(v, dd);
        if (lane >= dd) v += u;
    }
    if (lane == 63) wsum[w] = v;
    __syncthreads();
    int prefix = 0;
    #pragma unroll
    for (int i = 0; i < NT / 64; ++i) prefix += (i < w) ? wsum[i] : 0;
    const int base = prefix + v - s3;   // exclusive prefix for this thread's 4 elems
    cum[4 * t + 0] = base + s0;
    cum[4 * t + 1] = base + s1;
    cum[4 * t + 2] = base + s2;
    cum[4 * t + 3] = base + s3;
    __syncthreads();
    const int ml = cum[TT - 1];
    if (chunk == 0 && t == 0) mel_out[b] = (float)ml;

    // ---- searchsorted_right for this chunk's 128 rows (threads 0..127) ----
    if (t < ROWS) {
        int p = chunk * ROWS + t;
        int r = -1;
        if (p < ml) {
            int lo = 0, hi = TT;
            while (lo < hi) {            // lo = count(cum <= p)
                int mid = (lo + hi) >> 1;
                if (cum[mid] <= p) lo = mid + 1; else hi = mid;
            }
            r = (lo < TT - 1) ? lo : (TT - 1);
        }
        sidx[t] = r;
    }
    __syncthreads();

    // ---- stream 128 rows x 96 quads; coalesced loads, nontemporal stores ----
    const f32x4* __restrict__ xb = x4 + (size_t)b * TT * QPR;
    f32x4* __restrict__ ob = out4 + ((size_t)b * MAXLEN + (size_t)chunk * ROWS) * QPR;
    #pragma unroll 4
    for (int k = 0; k < ITERS; ++k) {
        unsigned q    = (unsigned)t + (unsigned)k * NT;
        unsigned row  = q / QPR;          // magic-mul, exact
        unsigned ln   = q - row * QPR;
        int i = sidx[row];
        f32x4 vv = (f32x4)0.f;
        if (i >= 0) vv = xb[(unsigned)i * QPR + ln];
        __builtin_nontemporal_store(vv, &ob[q]);
    }
}

extern "C" void kernel_launch(void* const* d_in, const int* in_sizes, int n_in,
                              void* d_out, int out_size, void* d_ws, size_t ws_size,
                              hipStream_t stream) {
    const float* x   = (const float*)d_in[0];
    const int*   dur = (const int*)d_in[1];   // int64 in reference -> int32 on device
    float* out = (float*)d_out;

    lr_fused<<<BB * 64, NT, 0, stream>>>((const int4*)dur, (const f32x4*)x,
                                         (f32x4*)out, out + OUT0);
}

// Round 6
// 89.914 us; speedup vs baseline: 1.0099x; 1.0047x over previous
//
#include <hip/hip_runtime.h>

// LengthRegulator, round 6: split prep + gather (R3 structure, measured best),
// with shuffle-scan prep and a stride-interleaved, load-balanced gather.
//   out[b,p,:] = x[b, searchsorted_right(cumsum(dur[b]), p), :]  (0 when p >= mel_len[b])
//   mel_len written as float at d_out + B*MAXLEN*C.
// B=32, T=1024, C=384, MAX_LEN=8192. Durations arrive as int32.

#define BB 32
#define TT 1024
#define CC 384
#define MAXLEN 8192
#define OUT0 (BB * MAXLEN * CC)   // 100663296 floats
#define QPR (CC / 4)              // 96 float4 per row
#define GBLK 2048
#define GTHR 256

typedef float f32x4 __attribute__((ext_vector_type(4)));

// ---------------- Kernel 1: prep (one block per batch) ----------------
// int4 load + serial 4-sum + 64-lane shfl scan + cross-wave fixup (2 barriers),
// then each thread binary-searches 32 positions; coalesced idx writes.
__global__ __launch_bounds__(256) void lr_prep(const int4* __restrict__ dur4,
                                               int* __restrict__ idx,
                                               float* __restrict__ mel_out) {
    __shared__ int cum[TT];
    __shared__ int wsum[4];
    const int b = blockIdx.x, t = threadIdx.x, lane = t & 63, w = t >> 6;

    int4 d = dur4[b * (TT / 4) + t];
    int s0 = d.x, s1 = s0 + d.y, s2 = s1 + d.z, s3 = s2 + d.w;
    int v = s3;
    #pragma unroll
    for (int dd = 1; dd < 64; dd <<= 1) {
        int u = __shfl_up(v, dd);
        if (lane >= dd) v += u;
    }
    if (lane == 63) wsum[w] = v;
    __syncthreads();
    int prefix = 0;
    #pragma unroll
    for (int i = 0; i < 4; ++i) prefix += (i < w) ? wsum[i] : 0;
    const int base = prefix + v - s3;          // exclusive prefix for this thread's 4
    cum[4 * t + 0] = base + s0;
    cum[4 * t + 1] = base + s1;
    cum[4 * t + 2] = base + s2;
    cum[4 * t + 3] = base + s3;
    __syncthreads();
    const int ml = cum[TT - 1];
    if (t == 0) mel_out[b] = (float)ml;

    #pragma unroll
    for (int k = 0; k < MAXLEN / 256; ++k) {   // 32 positions per thread
        int p = t + k * 256;
        int r = -1;
        if (p < ml) {
            int lo = 0, hi = TT;
            while (lo < hi) {                  // lo = count(cum <= p)
                int mid = (lo + hi) >> 1;
                if (cum[mid] <= p) lo = mid + 1; else hi = mid;
            }
            r = (lo < TT - 1) ? lo : (TT - 1);
        }
        idx[b * MAXLEN + p] = r;
    }
}

// ---------------- Kernel 2: gather ----------------
// Exact-fit 2048x256 grid. Stride-interleaved q mapping: consecutive
// iterations jump STEP quads (~5461 rows) so each thread gets a uniform
// heavy/light row mix -> no CU-level load imbalance. Two half-streams per
// iteration + unroll 2 = 4 independent load->NT-store chains in flight.
__global__ __launch_bounds__(GTHR) void lr_gather(const f32x4* __restrict__ x4,
                                                  const int* __restrict__ idx,
                                                  f32x4* __restrict__ out4) {
    const unsigned HALF = (unsigned)BB * MAXLEN * QPR / 2;  // 12582912
    const unsigned STEP = GBLK * GTHR;                      // 524288
    const unsigned gid = blockIdx.x * GTHR + threadIdx.x;
    #pragma unroll 2
    for (unsigned q = gid; q < HALF; q += STEP) {           // 24 iterations
        const unsigned q2 = q + HALF;
        unsigned row1 = q / QPR,  ln1 = q  - row1 * QPR;    // magic-mul, exact
        unsigned row2 = q2 / QPR, ln2 = q2 - row2 * QPR;
        int i1 = idx[row1];
        int i2 = idx[row2];
        f32x4 v1 = (f32x4)0.f, v2 = (f32x4)0.f;
        if (i1 >= 0) v1 = x4[((size_t)(row1 >> 13) * TT + (unsigned)i1) * QPR + ln1];
        if (i2 >= 0) v2 = x4[((size_t)(row2 >> 13) * TT + (unsigned)i2) * QPR + ln2];
        __builtin_nontemporal_store(v1, &out4[q]);
        __builtin_nontemporal_store(v2, &out4[q2]);
    }
}

extern "C" void kernel_launch(void* const* d_in, const int* in_sizes, int n_in,
                              void* d_out, int out_size, void* d_ws, size_t ws_size,
                              hipStream_t stream) {
    const float* x   = (const float*)d_in[0];
    const int*   dur = (const int*)d_in[1];   // int64 in reference -> int32 on device
    float* out = (float*)d_out;

    int* idx = (int*)d_ws;                    // B*MAXLEN int32 = 1 MB

    lr_prep<<<BB, 256, 0, stream>>>((const int4*)dur, idx, out + OUT0);
    lr_gather<<<GBLK, GTHR, 0, stream>>>((const f32x4*)x, idx, (f32x4*)out);
}